// Round 2
// baseline (868.949 us; speedup 1.0000x reference)
//
#include <hip/hip_runtime.h>
#include <math.h>

#define ITERS 30

// ws float offsets. ws[0..1023] is the int counter area (zeroed each launch).
#define PEND  1024            // 8*32*512 = 131072 floats: per-block LSE partials / col partials
#define GBUF  132096          // 4096 floats: g[b][m]
#define BPART 136192          // 256*8 floats: per-block epilogue partials

#define LN2f    0.69314718055994530942f
#define INVLN2  1.44269504088896340736f
#define K2c     2.40449173481494868463f   // 1/(0.6*ln2)
#define KCc     144.269504088896340736f   // 100/ln2
#define RKCc    0.0069314718055994530942f // ln2/100
#define CNEGc  -0.0067955605937249540f    // -eps*damping*ln2, damping=0.5/0.51
#define IRHOL2c 2.88539008177792681472f   // 1/(0.5*ln2)

__device__ __forceinline__ float fexp2(float x){ return __builtin_amdgcn_exp2f(x); }
__device__ __forceinline__ float flog2(float x){ return __builtin_amdgcn_logf(x); }
__device__ __forceinline__ float fsq(float x){ return __builtin_amdgcn_sqrtf(x); }

__device__ __forceinline__ float wave_max(float v){
  #pragma unroll
  for (int off = 1; off < 64; off <<= 1) v = fmaxf(v, __shfl_xor(v, off));
  return v;
}
__device__ __forceinline__ float wave_sum(float v){
  #pragma unroll
  for (int off = 1; off < 64; off <<= 1) v += __shfl_xor(v, off);
  return v;
}

// per-batch (target=32) / global (target=256) spin barrier, device-scope.
__device__ __forceinline__ void bar_sync(int* c, int target){
  __syncthreads();
  if (threadIdx.x == 0){
    __hip_atomic_fetch_add(c, 1, __ATOMIC_ACQ_REL, __HIP_MEMORY_SCOPE_AGENT);
    int spins = 0;
    while (__hip_atomic_load(c, __ATOMIC_ACQUIRE, __HIP_MEMORY_SCOPE_AGENT) < target){
      __builtin_amdgcn_s_sleep(1);
      if (++spins > (1 << 22)) break;   // safety escape: fail visibly, don't hang forever
    }
  }
  __syncthreads();
}

// One persistent block per CU. Block bb: batch b = bb>>5, n-strip s = bb&31
// (rows n = s*128 + w*8 + r). Lane l, slot k -> m = k*64 + l.
// Thread caches nK[r][k] = -KC * 2^(K2 * d(n,m)) in 64 VGPRs.
__global__ __launch_bounds__(1024, 4) void k_sink(const float* __restrict__ A,
                                                  const float* __restrict__ pts,
                                                  float* __restrict__ ws,
                                                  float* __restrict__ out){
  __shared__ float2 pms[512 * 17];   // [m][wave] (pm, ps) partials, padded
  __shared__ float red[80];
  const int tid = threadIdx.x, w = tid >> 6, l = tid & 63;
  const int bb = blockIdx.x, b = bb >> 5, s = bb & 31;
  int* cnt  = (int*)ws;
  int* cbat = cnt + b * 64;

  float nK[64];            // [r*8+k]
  float laK[8], P[8], G2[8], y[8];

  // ---- prologue: cost tile + log-mass; f0 = 0 -> P = la2 + KC = laK
  {
    float px[8], py[8];
    #pragma unroll
    for (int k = 0; k < 8; ++k){
      int m = k * 64 + l;
      px[k] = pts[(b*512 + m)*2 + 0] * (1.f/512.f);
      py[k] = pts[(b*512 + m)*2 + 1] * (1.f/512.f);
    }
    #pragma unroll
    for (int r = 0; r < 8; ++r){
      int n = s*128 + w*8 + r;
      float xn = (float)((n & 63) + 1) * (1.f/64.f);
      float yn = (float)((n >> 6) + 1) * (1.f/64.f);
      laK[r] = flog2(A[b*4096 + n] + 1e-20f) + KCc;
      P[r]   = laK[r];
      #pragma unroll
      for (int k = 0; k < 8; ++k){
        float dx = xn - px[k], dy = yn - py[k];
        float d2 = __builtin_fmaf(dy, dy, __builtin_fmaf(dx, dx, 1e-12f));
        nK[r*8 + k] = -KCc * fexp2(fsq(d2) * K2c);
      }
    }
  }

  // ---- 30 x { g-partial -> bar -> combine g -> bar -> f-update }
  #pragma unroll 1
  for (int it = 0; it < ITERS; ++it){
    // B: per-thread g-partials over this wave's 8 rows, merge 16 waves in LDS
    #pragma unroll
    for (int k = 0; k < 8; ++k){
      float pm = -INFINITY;
      #pragma unroll
      for (int r = 0; r < 8; ++r){ y[r] = P[r] + nK[r*8 + k]; pm = fmaxf(pm, y[r]); }
      float ps = 0.f;
      #pragma unroll
      for (int r = 0; r < 8; ++r) ps += fexp2(y[r] - pm);
      pms[(k*64 + l)*17 + w] = make_float2(pm, ps);
    }
    __syncthreads();
    if (tid < 512){
      int m = tid;
      float M = -INFINITY;
      #pragma unroll
      for (int q = 0; q < 16; ++q) M = fmaxf(M, pms[m*17 + q].x);
      float S = 0.f;
      #pragma unroll
      for (int q = 0; q < 16; ++q){ float2 v = pms[m*17 + q]; S += v.y * fexp2(v.x - M); }
      ws[PEND + (b*32 + s)*512 + m] = M + flog2(S);   // block-partial LSE2
    }
    bar_sync(cbat + 2*it, 32);

    // C: combine 32 block-partials; wave w owns m = s*16 + w
    {
      int mc = s*16 + w;
      float L = (l < 32) ? ws[PEND + (b*32 + l)*512 + mc] : -INFINITY;
      float M = wave_max(L);
      float S = wave_sum((l < 32) ? fexp2(L - M) : 0.f);
      float g = CNEGc * (M + flog2(S));
      if (l == 0) ws[GBUF + b*512 + mc] = g;
    }
    bar_sync(cbat + 2*it + 1, 32);

    // A: f-update, wave-internal over all 512 m
    #pragma unroll
    for (int k = 0; k < 8; ++k)
      G2[k] = __builtin_fmaf(ws[GBUF + b*512 + k*64 + l], KCc, KCc);
    #pragma unroll
    for (int r = 0; r < 8; ++r){
      float cm = -INFINITY;
      #pragma unroll
      for (int k = 0; k < 8; ++k){ y[k] = G2[k] + nK[r*8 + k]; cm = fmaxf(cm, y[k]); }
      float M = wave_max(cm);
      float sv = 0.f;
      #pragma unroll
      for (int k = 0; k < 8; ++k) sv += fexp2(y[k] - M);
      float S = wave_sum(sv);
      float f = CNEGc * (M + flog2(S));
      P[r] = __builtin_fmaf(f, KCc, laK[r]);   // P = f*KC + la2 + KC
    }
  }

  // ---- epilogue: PI-derived losses using cached tile (f30 in P, g30 in G2/GBUF)
  float ent = 0.f, pix = 0.f, emdf = 0.f, csum[8];
  #pragma unroll
  for (int k = 0; k < 8; ++k) csum[k] = 0.f;
  #pragma unroll
  for (int r = 0; r < 8; ++r){
    float base = P[r] - KCc;                 // f*KC + la2  (folds A into exponent)
    float An   = fexp2(laK[r] - KCc);
    float fr   = (P[r] - laK[r]) * RKCc;
    float rs = 0.f;
    #pragma unroll
    for (int k = 0; k < 8; ++k){
      float z = base + G2[k] + nK[r*8 + k];
      float p = fexp2(z);
      rs += p; csum[k] += p;
      float q = p + 1e-20f;
      ent = __builtin_fmaf(q * LN2f, flog2(q), ent);
    }
    float RS = wave_sum(rs);
    if (l == 0){
      pix  += fabsf(RS - An);
      emdf += An * (1.f - fexp2(fr * -IRHOL2c));
    }
  }
  // column partials (linear sums) -> global, then per-batch merge
  float* pmsf = (float*)pms;
  #pragma unroll
  for (int k = 0; k < 8; ++k) pmsf[(k*64 + l)*17 + w] = csum[k];
  __syncthreads();
  if (tid < 512){
    float cb = 0.f;
    #pragma unroll
    for (int q = 0; q < 16; ++q) cb += pmsf[tid*17 + q];
    ws[PEND + (b*32 + s)*512 + tid] = cb;
  }
  bar_sync(cbat + 60, 32);

  float pnt = 0.f;
  {
    int mc = s*16 + w;
    float v = (l < 32) ? ws[PEND + (b*32 + l)*512 + mc] : 0.f;
    float CS = wave_sum(v);
    if (l == 0) pnt = fabsf(CS - 1.f);
  }
  float emdg = 0.f;
  if (s == 0 && tid < 512){
    float g = ws[GBUF + b*512 + tid];
    emdg = 1.f - fexp2(g * -IRHOL2c);
  }
  ent = wave_sum(ent); pix = wave_sum(pix); emdf = wave_sum(emdf);
  pnt = wave_sum(pnt); emdg = wave_sum(emdg);
  if (l == 0){
    red[w*5+0] = ent; red[w*5+1] = pix; red[w*5+2] = emdf; red[w*5+3] = pnt; red[w*5+4] = emdg;
  }
  __syncthreads();
  if (tid == 0){
    float a0=0,a1=0,a2=0,a3=0,a4=0;
    for (int q = 0; q < 16; ++q){
      a0 += red[q*5+0]; a1 += red[q*5+1]; a2 += red[q*5+2]; a3 += red[q*5+3]; a4 += red[q*5+4];
    }
    float* bp = ws + BPART + bb*8;
    bp[0]=a0; bp[1]=a1; bp[2]=a2; bp[3]=a3; bp[4]=a4;
  }

  bar_sync(cnt + 512, 256);   // global barrier

  if (bb == 0){
    float v0=0,v1=0,v2=0,v3=0,v4=0;
    if (tid < 256){
      const float* bp = ws + BPART + tid*8;
      v0=bp[0]; v1=bp[1]; v2=bp[2]; v3=bp[3]; v4=bp[4];
    }
    v0=wave_sum(v0); v1=wave_sum(v1); v2=wave_sum(v2); v3=wave_sum(v3); v4=wave_sum(v4);
    if (l == 0){
      red[w*5+0]=v0; red[w*5+1]=v1; red[w*5+2]=v2; red[w*5+3]=v3; red[w*5+4]=v4;
    }
    __syncthreads();
    if (tid == 0){
      float E=0,PX=0,EF=0,PT=0,EG=0;
      for (int q = 0; q < 16; ++q){
        E += red[q*5+0]; PX += red[q*5+1]; EF += red[q*5+2]; PT += red[q*5+3]; EG += red[q*5+4];
      }
      float emd = 0.5f * (EF + EG);
      out[0] = emd + 0.1f * (PX + PT) + 0.01f * (E * (1.f / (4096.f * 512.f)));
    }
  }
}

extern "C" void kernel_launch(void* const* d_in, const int* in_sizes, int n_in,
                              void* d_out, int out_size, void* d_ws, size_t ws_size,
                              hipStream_t stream) {
  const float* A   = (const float*)d_in[0];   // predict_map [8,1,64,64]
  const float* pts = (const float*)d_in[1];   // points [8,512,2]
  float* ws  = (float*)d_ws;
  float* out = (float*)d_out;

  hipMemsetAsync(d_ws, 0, 4096, stream);      // zero barrier counters every call
  k_sink<<<256, 1024, 0, stream>>>(A, pts, ws, out);
}